// Round 2
// baseline (3218.341 us; speedup 1.0000x reference)
//
#include <hip/hip_runtime.h>
#include <hip/hip_bf16.h>
#include <math.h>

#define D 128
#define NG 512
#define NC 10
#define BN_EPS 1e-5f

// ---------------- utility ----------------
__global__ void zero_ints(int* __restrict__ p, int n) {
    int i = blockIdx.x * blockDim.x + threadIdx.x;
    int s = gridDim.x * blockDim.x;
    for (; i < n; i += s) p[i] = 0;
}

__global__ void hist_i32(const int* __restrict__ v, int n, int* __restrict__ cnt) {
    int i = blockIdx.x * blockDim.x + threadIdx.x;
    int s = gridDim.x * blockDim.x;
    for (; i < n; i += s) atomicAdd(&cnt[v[i]], 1);
}

// single-block exclusive scan over n<=1024*chunk counters; writes start[0..n] (start[n]=total)
__global__ void scan_small(const int* __restrict__ cnt, int n, int* __restrict__ start,
                           int* __restrict__ cursor) {
    __shared__ int part[1024];
    int tid = threadIdx.x;
    int chunk = (n + 1023) >> 10;
    int lo = tid * chunk, hi = lo + chunk;
    if (hi > n) hi = n;
    int s = 0;
    for (int i = lo; i < hi; ++i) s += cnt[i];
    part[tid] = s;
    __syncthreads();
    for (int off = 1; off < 1024; off <<= 1) {
        int v = (tid >= off) ? part[tid - off] : 0;
        __syncthreads();
        part[tid] += v;
        __syncthreads();
    }
    int run = tid ? part[tid - 1] : 0;
    for (int i = lo; i < hi; ++i) {
        int c = cnt[i];
        start[i] = run;
        if (cursor) cursor[i] = run;
        run += c;
    }
    if (tid == 1023) start[n] = part[1023];
}

__global__ void fill_csr(const int* __restrict__ srcs, const int* __restrict__ dsts, int E,
                         int* __restrict__ cursor, int* __restrict__ csr_src) {
    int i = blockIdx.x * blockDim.x + threadIdx.x;
    int s = gridDim.x * blockDim.x;
    for (; i < E; i += s) {
        int d = dsts[i];
        int pos = atomicAdd(&cursor[d], 1);
        csr_src[pos] = srcs[i];
    }
}

// ---------------- aggregation: z_n = affine(src_n + sum_{e in in(n)} src_{csr[e]}) ----------------
// affine folds the PREVIOUS layer's BatchNorm: h = z2*a + b  =>  z = (z2_n + sum z2_src)*a + (1+deg)*b
__global__ void agg_kernel(const float* __restrict__ srcmat, const float* __restrict__ stats,
                           const float* __restrict__ gamma, const float* __restrict__ beta,
                           float invN, const int* __restrict__ row_start,
                           const int* __restrict__ csr_src, float* __restrict__ out, int N) {
    int gtid = blockIdx.x * blockDim.x + threadIdx.x;
    int wid = gtid >> 6;
    int lane = gtid & 63;
    int nw = (gridDim.x * blockDim.x) >> 6;
    int c = lane * 2;
    float a0 = 1.f, b0 = 0.f, a1 = 1.f, b1 = 0.f;
    if (stats) {
        float m0 = stats[c] * invN, m1 = stats[c + 1] * invN;
        float v0 = fmaxf(stats[D + c] * invN - m0 * m0, 0.f);
        float v1 = fmaxf(stats[D + c + 1] * invN - m1 * m1, 0.f);
        float r0 = rsqrtf(v0 + BN_EPS), r1 = rsqrtf(v1 + BN_EPS);
        a0 = r0 * gamma[c];     b0 = beta[c] - m0 * a0;
        a1 = r1 * gamma[c + 1]; b1 = beta[c + 1] - m1 * a1;
    }
    const float2* base = (const float2*)srcmat;
    for (int n = wid; n < N; n += nw) {
        float2 acc = base[(size_t)n * 64 + lane];
        int e0 = row_start[n], e1 = row_start[n + 1];
        for (int e = e0; e < e1; ++e) {
            int sidx = csr_src[e];
            float2 v = base[(size_t)sidx * 64 + lane];
            acc.x += v.x;
            acc.y += v.y;
        }
        float db = (float)(e1 - e0 + 1);
        float2 o;
        o.x = acc.x * a0 + db * b0;
        o.y = acc.y * a1 + db * b1;
        *(float2*)(out + (size_t)n * D + c) = o;
    }
}

// ---------------- fp32 tiled GEMM: out = relu(in @ W + bias), in-place safe (LDS staged) ----------------
__device__ __forceinline__ void fma4(float4& acc, float s, const float4& w) {
    acc.x = fmaf(s, w.x, acc.x);
    acc.y = fmaf(s, w.y, acc.y);
    acc.z = fmaf(s, w.z, acc.z);
    acc.w = fmaf(s, w.w, acc.w);
}

__launch_bounds__(256, 2)
__global__ void gemm_relu(const float* in, const float* __restrict__ W,
                          const float* __restrict__ bias, float* out, int N) {
    __shared__ float zt[32 * D];   // 16 KB
    __shared__ float wt[D * D];    // 64 KB
    int tid = threadIdx.x;
    int rb = blockIdx.x << 5;

    const float4* Wf = (const float4*)W;
    float4* wtf = (float4*)wt;
#pragma unroll
    for (int p = 0; p < 16; ++p) wtf[tid + p * 256] = Wf[tid + p * 256];

    const float4* inf = (const float4*)in;
    float4* ztf = (float4*)zt;
#pragma unroll
    for (int p = 0; p < 4; ++p) {
        int idx = tid + p * 256;
        int r = idx >> 5;
        int rg = rb + r;
        float4 v = {0.f, 0.f, 0.f, 0.f};
        if (rg < N) v = inf[(size_t)rg * 32 + (idx & 31)];
        ztf[idx] = v;
    }
    __syncthreads();

    int tc = tid & 31, tr = tid >> 5;
    int r0 = tr << 2;
    float4 bz = ((const float4*)bias)[tc];
    float4 a0 = bz, a1 = bz, a2 = bz, a3 = bz;
    const float4* zf = (const float4*)zt;
    const float4* wf = (const float4*)wt;
#pragma unroll 8
    for (int k4 = 0; k4 < 32; ++k4) {
        float4 z0 = zf[(r0 + 0) * 32 + k4];
        float4 z1 = zf[(r0 + 1) * 32 + k4];
        float4 z2 = zf[(r0 + 2) * 32 + k4];
        float4 z3 = zf[(r0 + 3) * 32 + k4];
        float4 w0 = wf[(k4 * 4 + 0) * 32 + tc];
        float4 w1 = wf[(k4 * 4 + 1) * 32 + tc];
        float4 w2 = wf[(k4 * 4 + 2) * 32 + tc];
        float4 w3 = wf[(k4 * 4 + 3) * 32 + tc];
        fma4(a0, z0.x, w0); fma4(a0, z0.y, w1); fma4(a0, z0.z, w2); fma4(a0, z0.w, w3);
        fma4(a1, z1.x, w0); fma4(a1, z1.y, w1); fma4(a1, z1.z, w2); fma4(a1, z1.w, w3);
        fma4(a2, z2.x, w0); fma4(a2, z2.y, w1); fma4(a2, z2.z, w2); fma4(a2, z2.w, w3);
        fma4(a3, z3.x, w0); fma4(a3, z3.y, w1); fma4(a3, z3.z, w2); fma4(a3, z3.w, w3);
    }
    float4* of = (float4*)out;
#define RELU4(A) A.x = fmaxf(A.x, 0.f); A.y = fmaxf(A.y, 0.f); A.z = fmaxf(A.z, 0.f); A.w = fmaxf(A.w, 0.f)
    RELU4(a0); RELU4(a1); RELU4(a2); RELU4(a3);
    int rg = rb + r0;
    if (rg + 0 < N) of[(size_t)(rg + 0) * 32 + tc] = a0;
    if (rg + 1 < N) of[(size_t)(rg + 1) * 32 + tc] = a1;
    if (rg + 2 < N) of[(size_t)(rg + 2) * 32 + tc] = a2;
    if (rg + 3 < N) of[(size_t)(rg + 3) * 32 + tc] = a3;
}

// ---------------- per-graph pooling + global column stats of z ----------------
__global__ void pool_stats(const float* __restrict__ z, const int* __restrict__ gstart,
                           float* __restrict__ pool, float* __restrict__ stats) {
    int g = blockIdx.x;
    int tid = threadIdx.x;  // 256
    int col = tid & 127;
    int half = tid >> 7;
    int r0 = gstart[g], r1 = gstart[g + 1];
    float s = 0.f, sq = 0.f;
    for (int r = r0 + half; r < r1; r += 2) {
        float v = z[(size_t)r * D + col];
        s += v;
        sq += v * v;
    }
    __shared__ float red[256];
    red[tid] = s;
    __syncthreads();
    if (half == 0) {
        float tot = red[tid] + red[tid + 128];
        pool[g * D + col] = tot;
        if (stats) atomicAdd(&stats[col], tot);
    }
    __syncthreads();
    red[tid] = sq;
    __syncthreads();
    if (half == 0 && stats) {
        float tot = red[tid] + red[tid + 128];
        atomicAdd(&stats[D + col], tot);
    }
}

// ---------------- graph FC: y = relu((gprev + pool*a + cnt*b) @ W + bias), accumulate y column stats ----------------
__global__ void fc_forward(const float* __restrict__ pool, const float* __restrict__ stats,
                           const float* __restrict__ gamma, const float* __restrict__ beta,
                           float invN, const int* __restrict__ gstart, const float* __restrict__ gprev,
                           const float* __restrict__ W, const float* __restrict__ bias,
                           float* __restrict__ y, float* __restrict__ ystats) {
    int g = blockIdx.x;     // NG
    int tid = threadIdx.x;  // D
    __shared__ float u[D];
    float pv = pool[g * D + tid];
    float uv;
    if (stats) {
        float m = stats[tid] * invN;
        float var = fmaxf(stats[D + tid] * invN - m * m, 0.f);
        float rs = rsqrtf(var + BN_EPS);
        float a = rs * gamma[tid];
        float b = beta[tid] - m * a;
        float cntg = (float)(gstart[g + 1] - gstart[g]);
        uv = gprev[g * D + tid] + pv * a + cntg * b;
    } else {
        uv = pv;
    }
    u[tid] = uv;
    __syncthreads();
    float acc = bias[tid];
#pragma unroll 8
    for (int k = 0; k < D; ++k) acc = fmaf(u[k], W[k * D + tid], acc);
    acc = fmaxf(acc, 0.f);
    y[g * D + tid] = acc;
    atomicAdd(&ystats[tid], acc);
    atomicAdd(&ystats[D + tid], acc * acc);
}

// ---------------- BN over G rows + total accumulate ----------------
__global__ void fc_bn(const float* __restrict__ y, const float* __restrict__ ystats,
                      const float* __restrict__ gamma, const float* __restrict__ beta,
                      float* __restrict__ gbuf, float* __restrict__ total, int first) {
    int idx = blockIdx.x * blockDim.x + threadIdx.x;  // NG*D
    int d = idx & 127;
    const float invG = 1.f / NG;
    float m = ystats[d] * invG;
    float var = fmaxf(ystats[D + d] * invG - m * m, 0.f);
    float rs = rsqrtf(var + BN_EPS);
    float gv = (y[idx] - m) * rs * gamma[d] + beta[d];
    gbuf[idx] = gv;
    total[idx] = first ? gv : (total[idx] + gv);
}

// ---------------- final classifier + log_softmax ----------------
__global__ void final_logits(const float* __restrict__ total, const float* __restrict__ linW,
                             const float* __restrict__ linb, float* __restrict__ out) {
    int g = blockIdx.x;
    int tid = threadIdx.x;  // D
    __shared__ float t[D];
    __shared__ float lg[12];
    t[tid] = total[g * D + tid];
    __syncthreads();
    if (tid < NC) {
        float a = linb[tid];
        for (int k = 0; k < D; ++k) a = fmaf(t[k], linW[k * NC + tid], a);
        lg[tid] = a;
    }
    __syncthreads();
    if (tid == 0) {
        float mx = lg[0];
        for (int c = 1; c < NC; ++c) mx = fmaxf(mx, lg[c]);
        float se = 0.f;
        for (int c = 0; c < NC; ++c) se += expf(lg[c] - mx);
        lg[10] = mx + logf(se);
    }
    __syncthreads();
    if (tid < NC) out[g * NC + tid] = lg[tid] - lg[10];
}

// ---------------- host ----------------
extern "C" void kernel_launch(void* const* d_in, const int* in_sizes, int n_in,
                              void* d_out, int out_size, void* d_ws, size_t ws_size,
                              hipStream_t stream) {
    const float* x = (const float*)d_in[0];
    const int* edge = (const int*)d_in[1];      // int64 in reference -> int32 from harness
    const int* batch = (const int*)d_in[2];     // int64 in reference -> int32 from harness
    const float* convW1 = (const float*)d_in[3];
    const float* convb1 = (const float*)d_in[4];
    const float* convW2 = (const float*)d_in[5];
    const float* convb2 = (const float*)d_in[6];
    const float* convgamma = (const float*)d_in[7];
    const float* convbeta = (const float*)d_in[8];
    const float* fc1W = (const float*)d_in[9];
    const float* fc1b = (const float*)d_in[10];
    const float* fc1gamma = (const float*)d_in[11];
    const float* fc1beta = (const float*)d_in[12];
    const float* fc2W = (const float*)d_in[13];
    const float* fc2b = (const float*)d_in[14];
    const float* fc2gamma = (const float*)d_in[15];
    const float* fc2beta = (const float*)d_in[16];
    const float* linW = (const float*)d_in[17];
    const float* linb = (const float*)d_in[18];

    const int N = in_sizes[0] / D;
    const int E = in_sizes[1] / 2;
    const int* srcs = edge;
    const int* dsts = edge + E;
    const float invN = 1.f / (float)N;

    // workspace carve (aligned 256B)
    char* p = (char*)d_ws;
    auto alloc = [&](size_t bytes) -> void* {
        void* r = (void*)p;
        p += (bytes + 255) & ~(size_t)255;
        return r;
    };
    float* zA = (float*)alloc((size_t)N * D * 4);
    float* zB = (float*)alloc((size_t)N * D * 4);
    int* csr = (int*)alloc((size_t)E * 4);
    int* row_start = (int*)alloc((size_t)(N + 1) * 4);
    int* cursor = (int*)alloc((size_t)N * 4);
    int* cnt = (int*)alloc((size_t)N * 4);
    int* gstart = (int*)alloc((size_t)(NG + 1) * 4);
    int* ghist = (int*)alloc((size_t)NG * 4);
    float* pool = (float*)alloc((size_t)NG * D * 4);
    float* stats = (float*)alloc((size_t)2 * D * 4);
    float* ystats = (float*)alloc((size_t)2 * D * 4);
    float* ybuf = (float*)alloc((size_t)NG * D * 4);
    float* gbuf = (float*)alloc((size_t)NG * D * 4);
    float* total = (float*)alloc((size_t)NG * D * 4);

    // ---- preprocessing: CSR by dst, graph row ranges ----
    zero_ints<<<256, 256, 0, stream>>>(cnt, N);
    zero_ints<<<2, 256, 0, stream>>>(ghist, NG);
    hist_i32<<<2048, 256, 0, stream>>>(dsts, E, cnt);
    hist_i32<<<512, 256, 0, stream>>>(batch, N, ghist);
    scan_small<<<1, 1024, 0, stream>>>(cnt, N, row_start, cursor);
    scan_small<<<1, 1024, 0, stream>>>(ghist, NG, gstart, nullptr);
    fill_csr<<<2048, 256, 0, stream>>>(srcs, dsts, E, cursor, csr);

    // ---- g0 = BN(relu(pool(x) @ fc1W + fc1b)) ; total = g0 ----
    pool_stats<<<NG, 256, 0, stream>>>(x, gstart, pool, nullptr);
    zero_ints<<<1, 256, 0, stream>>>((int*)ystats, 2 * D);
    fc_forward<<<NG, D, 0, stream>>>(pool, nullptr, nullptr, nullptr, 0.f, nullptr, nullptr,
                                     fc1W, fc1b, ybuf, ystats);
    fc_bn<<<(NG * D) / 256, 256, 0, stream>>>(ybuf, ystats, fc1gamma, fc1beta, gbuf, total, 1);

    // ---- 5 GIN layers ----
    const float* src = x;
    const int gemm_grid = (N + 31) / 32;
    for (int i = 0; i < 5; ++i) {
        const float* st = (i == 0) ? nullptr : stats;
        const float* ga = (i == 0) ? nullptr : (convgamma + (size_t)(i - 1) * D);
        const float* be = (i == 0) ? nullptr : (convbeta + (size_t)(i - 1) * D);
        agg_kernel<<<2048, 256, 0, stream>>>(src, st, ga, be, invN, row_start, csr, zA, N);
        gemm_relu<<<gemm_grid, 256, 0, stream>>>(zA, convW1 + (size_t)i * D * D, convb1 + (size_t)i * D, zA, N);
        gemm_relu<<<gemm_grid, 256, 0, stream>>>(zA, convW2 + (size_t)i * D * D, convb2 + (size_t)i * D, zB, N);
        zero_ints<<<1, 256, 0, stream>>>((int*)stats, 2 * D);
        pool_stats<<<NG, 256, 0, stream>>>(zB, gstart, pool, stats);
        zero_ints<<<1, 256, 0, stream>>>((int*)ystats, 2 * D);
        fc_forward<<<NG, D, 0, stream>>>(pool, stats, convgamma + (size_t)i * D, convbeta + (size_t)i * D,
                                         invN, gstart, gbuf, fc2W, fc2b, ybuf, ystats);
        fc_bn<<<(NG * D) / 256, 256, 0, stream>>>(ybuf, ystats, fc2gamma, fc2beta, gbuf, total, 0);
        src = zB;
    }

    // ---- classifier ----
    final_logits<<<NG, D, 0, stream>>>(total, linW, linb, (float*)d_out);
}

// Round 3
// 2180.640 us; speedup vs baseline: 1.4759x; 1.4759x over previous
//
#include <hip/hip_runtime.h>
#include <hip/hip_bf16.h>
#include <math.h>

#define D 128
#define NG 512
#define NC 10
#define BN_EPS 1e-5f

typedef __attribute__((ext_vector_type(8))) short frag_ab;  // 8 bf16 = 4 VGPR
typedef __attribute__((ext_vector_type(4))) float f32x4;

__device__ __forceinline__ ushort f2bf(float v) {
    __hip_bfloat16 h = __float2bfloat16(v);
    union { __hip_bfloat16 h; ushort u; } c;
    c.h = h;
    return c.u;
}
__device__ __forceinline__ float bflo(uint u) { return __uint_as_float(u << 16); }
__device__ __forceinline__ float bfhi(uint u) { return __uint_as_float(u & 0xffff0000u); }
__device__ __forceinline__ uint packbf(float x, float y) {
    return (uint)f2bf(x) | ((uint)f2bf(y) << 16);
}

// ---------------- utility ----------------
__global__ void zero_ints(int* __restrict__ p, int n) {
    int i = blockIdx.x * blockDim.x + threadIdx.x;
    int s = gridDim.x * blockDim.x;
    for (; i < n; i += s) p[i] = 0;
}

__global__ void hist_i32(const int* __restrict__ v, int n, int* __restrict__ cnt) {
    int i = blockIdx.x * blockDim.x + threadIdx.x;
    int s = gridDim.x * blockDim.x;
    for (; i < n; i += s) atomicAdd(&cnt[v[i]], 1);
}

__global__ void scan_small(const int* __restrict__ cnt, int n, int* __restrict__ start,
                           int* __restrict__ cursor) {
    __shared__ int part[1024];
    int tid = threadIdx.x;
    int chunk = (n + 1023) >> 10;
    int lo = tid * chunk, hi = lo + chunk;
    if (hi > n) hi = n;
    int s = 0;
    for (int i = lo; i < hi; ++i) s += cnt[i];
    part[tid] = s;
    __syncthreads();
    for (int off = 1; off < 1024; off <<= 1) {
        int v = (tid >= off) ? part[tid - off] : 0;
        __syncthreads();
        part[tid] += v;
        __syncthreads();
    }
    int run = tid ? part[tid - 1] : 0;
    for (int i = lo; i < hi; ++i) {
        int c = cnt[i];
        start[i] = run;
        if (cursor) cursor[i] = run;
        run += c;
    }
    if (tid == 1023) start[n] = part[1023];
}

__global__ void fill_csr(const int* __restrict__ srcs, const int* __restrict__ dsts, int E,
                         int* __restrict__ cursor, int* __restrict__ csr_src) {
    int i = blockIdx.x * blockDim.x + threadIdx.x;
    int s = gridDim.x * blockDim.x;
    for (; i < E; i += s) {
        int d = dsts[i];
        int pos = atomicAdd(&cursor[d], 1);
        csr_src[pos] = srcs[i];
    }
}

// ---------------- fp32 -> bf16x2 convert (x) ----------------
__global__ void cvt_bf16(const float* __restrict__ in, uint* __restrict__ out, int nPairs) {
    int i = blockIdx.x * blockDim.x + threadIdx.x;
    int s = gridDim.x * blockDim.x;
    const float2* in2 = (const float2*)in;
    for (; i < nPairs; i += s) {
        float2 v = in2[i];
        out[i] = packbf(v.x, v.y);
    }
}

// ---------------- weight prep: Wt[n][k] = bf16(W[k][n]), 10 matrices ----------------
__global__ void prep_w(const float* __restrict__ W1, const float* __restrict__ W2,
                       ushort* __restrict__ Wt) {
    int m = blockIdx.x;
    const float* W = (m < 5) ? (W1 + (size_t)m * D * D) : (W2 + (size_t)(m - 5) * D * D);
    ushort* out = Wt + (size_t)m * D * D;
    __shared__ ushort ws[D * D];
    int tid = threadIdx.x;
    for (int i = tid; i < D * D; i += 256) ws[i] = f2bf(W[i]);
    __syncthreads();
    int n = tid >> 1, kh = (tid & 1) << 6;
    uint* op = (uint*)(out + n * D + kh);
#pragma unroll 8
    for (int j = 0; j < 32; ++j) {
        uint lo = ws[(kh + 2 * j) * D + n];
        uint hi = ws[(kh + 2 * j + 1) * D + n];
        op[j] = lo | (hi << 16);
    }
}

// ---------------- aggregation (bf16 in / bf16 out, fp32 accum, BN-fold) ----------------
__global__ void agg_kernel(const uint* __restrict__ src, const float* __restrict__ stats,
                           const float* __restrict__ gamma, const float* __restrict__ beta,
                           float invN, const int* __restrict__ row_start,
                           const int* __restrict__ csr_src, uint* __restrict__ out, int N) {
    int gtid = blockIdx.x * blockDim.x + threadIdx.x;
    int wid = gtid >> 6;
    int lane = gtid & 63;
    int nw = (gridDim.x * blockDim.x) >> 6;
    int c = lane * 2;
    float a0 = 1.f, b0 = 0.f, a1 = 1.f, b1 = 0.f;
    if (stats) {
        float m0 = stats[c] * invN, m1 = stats[c + 1] * invN;
        float v0 = fmaxf(stats[D + c] * invN - m0 * m0, 0.f);
        float v1 = fmaxf(stats[D + c + 1] * invN - m1 * m1, 0.f);
        float r0 = rsqrtf(v0 + BN_EPS), r1 = rsqrtf(v1 + BN_EPS);
        a0 = r0 * gamma[c];     b0 = beta[c] - m0 * a0;
        a1 = r1 * gamma[c + 1]; b1 = beta[c + 1] - m1 * a1;
    }
    for (int n = wid; n < N; n += nw) {
        uint u = src[(size_t)n * 64 + lane];
        float x0 = bflo(u), y0 = bfhi(u);
        float x1 = 0.f, y1 = 0.f, x2 = 0.f, y2 = 0.f, x3 = 0.f, y3 = 0.f;
        int e = row_start[n], e1v = row_start[n + 1];
        int deg = e1v - e;
        for (; e + 3 < e1v; e += 4) {
            int s0 = csr_src[e], s1 = csr_src[e + 1], s2 = csr_src[e + 2], s3 = csr_src[e + 3];
            uint u0 = src[(size_t)s0 * 64 + lane];
            uint u1 = src[(size_t)s1 * 64 + lane];
            uint u2 = src[(size_t)s2 * 64 + lane];
            uint u3 = src[(size_t)s3 * 64 + lane];
            x0 += bflo(u0); y0 += bfhi(u0);
            x1 += bflo(u1); y1 += bfhi(u1);
            x2 += bflo(u2); y2 += bfhi(u2);
            x3 += bflo(u3); y3 += bfhi(u3);
        }
        for (; e < e1v; ++e) {
            uint u0 = src[(size_t)csr_src[e] * 64 + lane];
            x1 += bflo(u0); y1 += bfhi(u0);
        }
        float sx = (x0 + x1) + (x2 + x3);
        float sy = (y0 + y1) + (y2 + y3);
        float db = (float)(deg + 1);
        out[(size_t)n * 64 + lane] = packbf(sx * a0 + db * b0, sy * a1 + db * b1);
    }
}

// ---------------- MFMA GEMM: out = relu(z @ W + b), bf16 in/out, fp32 accum ----------------
// z: N x 128 bf16 row-major; Wt: 128(n) x 128(k) bf16 (pre-transposed); per-wave 16 rows.
__launch_bounds__(256, 4)
__global__ void gemm_mfma(const uint* __restrict__ z, const ushort* __restrict__ wt,
                          const float* __restrict__ bias, uint* __restrict__ outp, int N) {
    int tid = threadIdx.x;
    int lane = tid & 63;
    int wv = tid >> 6;
    int col = lane & 15;
    int kq = lane >> 4;          // 0..3 k-quarter
    int blk = blockIdx.x;
    int m0 = blk * 64 + wv * 16;

    const char* zb = (const char*)z;
    const char* wb = (const char*)wt;

    // A fragments: row = m0+col, k = kc*32 + kq*8 .. +8
    int arow = m0 + col;
    if (arow >= N) arow = N - 1;
    const char* zrow = zb + (size_t)arow * 256 + kq * 16;
    frag_ab a0 = *(const frag_ab*)(zrow);
    frag_ab a1 = *(const frag_ab*)(zrow + 64);
    frag_ab a2 = *(const frag_ab*)(zrow + 128);
    frag_ab a3 = *(const frag_ab*)(zrow + 192);

    f32x4 acc[8];
#pragma unroll
    for (int n = 0; n < 8; ++n) {
        float bz = bias[n * 16 + col];
        acc[n] = (f32x4){bz, bz, bz, bz};
    }

    const char* wl = wb + (size_t)col * 256 + kq * 16;  // + n*4096 + kc*64
#pragma unroll
    for (int kc = 0; kc < 4; ++kc) {
        frag_ab b0 = *(const frag_ab*)(wl + 0 * 4096 + kc * 64);
        frag_ab b1 = *(const frag_ab*)(wl + 1 * 4096 + kc * 64);
        frag_ab b2 = *(const frag_ab*)(wl + 2 * 4096 + kc * 64);
        frag_ab b3 = *(const frag_ab*)(wl + 3 * 4096 + kc * 64);
        frag_ab b4 = *(const frag_ab*)(wl + 4 * 4096 + kc * 64);
        frag_ab b5 = *(const frag_ab*)(wl + 5 * 4096 + kc * 64);
        frag_ab b6 = *(const frag_ab*)(wl + 6 * 4096 + kc * 64);
        frag_ab b7 = *(const frag_ab*)(wl + 7 * 4096 + kc * 64);
        frag_ab av = (kc == 0) ? a0 : (kc == 1) ? a1 : (kc == 2) ? a2 : a3;
        acc[0] = __builtin_amdgcn_mfma_f32_16x16x32_bf16(av, b0, acc[0], 0, 0, 0);
        acc[1] = __builtin_amdgcn_mfma_f32_16x16x32_bf16(av, b1, acc[1], 0, 0, 0);
        acc[2] = __builtin_amdgcn_mfma_f32_16x16x32_bf16(av, b2, acc[2], 0, 0, 0);
        acc[3] = __builtin_amdgcn_mfma_f32_16x16x32_bf16(av, b3, acc[3], 0, 0, 0);
        acc[4] = __builtin_amdgcn_mfma_f32_16x16x32_bf16(av, b4, acc[4], 0, 0, 0);
        acc[5] = __builtin_amdgcn_mfma_f32_16x16x32_bf16(av, b5, acc[5], 0, 0, 0);
        acc[6] = __builtin_amdgcn_mfma_f32_16x16x32_bf16(av, b6, acc[6], 0, 0, 0);
        acc[7] = __builtin_amdgcn_mfma_f32_16x16x32_bf16(av, b7, acc[7], 0, 0, 0);
    }

    // epilogue: relu -> bf16 -> LDS -> coalesced store
    __shared__ __align__(16) ushort cs[64 * D];
    int rbase = wv * 16 + kq * 4;
#pragma unroll
    for (int n = 0; n < 8; ++n) {
#pragma unroll
        for (int r = 0; r < 4; ++r) {
            float v = fmaxf(acc[n][r], 0.f);
            cs[(rbase + r) * D + n * 16 + col] = f2bf(v);
        }
    }
    __syncthreads();
    const uint4* csv = (const uint4*)cs;
    uint4* og = (uint4*)outp;
#pragma unroll
    for (int p = 0; p < 4; ++p) {
        int idx = p * 256 + tid;       // uint4 index within 64x128 tile (16 per row)
        int row = blk * 64 + (idx >> 4);
        if (row < N) og[(size_t)blk * 1024 + idx] = csv[idx];
    }
}

// ---------------- per-graph pooling + global column stats ----------------
template <int BF16>
__global__ void pool_stats(const void* __restrict__ zptr, const int* __restrict__ gstart,
                           float* __restrict__ pool, float* __restrict__ stats) {
    int g = blockIdx.x;
    int tid = threadIdx.x;  // 256
    int r0 = gstart[g], r1 = gstart[g + 1];
    __shared__ float red[256];
    if (BF16) {
        const uint* z = (const uint*)zptr;
        int uc = tid & 63;
        int qq = tid >> 6;
        float s0 = 0.f, s1 = 0.f, q0 = 0.f, q1 = 0.f;
        for (int r = r0 + qq; r < r1; r += 4) {
            uint u = z[(size_t)r * 64 + uc];
            float lo = bflo(u), hi = bfhi(u);
            s0 += lo; s1 += hi;
            q0 += lo * lo; q1 += hi * hi;
        }
        float S0 = 0.f, S1 = 0.f, Q0 = 0.f, Q1 = 0.f;
        red[tid] = s0; __syncthreads();
        if (qq == 0) S0 = red[uc] + red[uc + 64] + red[uc + 128] + red[uc + 192];
        __syncthreads();
        red[tid] = s1; __syncthreads();
        if (qq == 0) S1 = red[uc] + red[uc + 64] + red[uc + 128] + red[uc + 192];
        __syncthreads();
        red[tid] = q0; __syncthreads();
        if (qq == 0) Q0 = red[uc] + red[uc + 64] + red[uc + 128] + red[uc + 192];
        __syncthreads();
        red[tid] = q1; __syncthreads();
        if (qq == 0) Q1 = red[uc] + red[uc + 64] + red[uc + 128] + red[uc + 192];
        if (qq == 0) {
            pool[g * D + 2 * uc] = S0;
            pool[g * D + 2 * uc + 1] = S1;
            if (stats) {
                atomicAdd(&stats[2 * uc], S0);
                atomicAdd(&stats[2 * uc + 1], S1);
                atomicAdd(&stats[D + 2 * uc], Q0);
                atomicAdd(&stats[D + 2 * uc + 1], Q1);
            }
        }
    } else {
        const float* z = (const float*)zptr;
        int col = tid & 127;
        int half = tid >> 7;
        float s = 0.f;
        for (int r = r0 + half; r < r1; r += 2) s += z[(size_t)r * D + col];
        red[tid] = s;
        __syncthreads();
        if (half == 0) pool[g * D + col] = red[tid] + red[tid + 128];
    }
}

// ---------------- graph FC ----------------
__global__ void fc_forward(const float* __restrict__ pool, const float* __restrict__ stats,
                           const float* __restrict__ gamma, const float* __restrict__ beta,
                           float invN, const int* __restrict__ gstart, const float* __restrict__ gprev,
                           const float* __restrict__ W, const float* __restrict__ bias,
                           float* __restrict__ y, float* __restrict__ ystats) {
    int g = blockIdx.x;     // NG
    int tid = threadIdx.x;  // D
    __shared__ float u[D];
    float pv = pool[g * D + tid];
    float uv;
    if (stats) {
        float m = stats[tid] * invN;
        float var = fmaxf(stats[D + tid] * invN - m * m, 0.f);
        float rs = rsqrtf(var + BN_EPS);
        float a = rs * gamma[tid];
        float b = beta[tid] - m * a;
        float cntg = (float)(gstart[g + 1] - gstart[g]);
        uv = gprev[g * D + tid] + pv * a + cntg * b;
    } else {
        uv = pv;
    }
    u[tid] = uv;
    __syncthreads();
    float acc = bias[tid];
#pragma unroll 8
    for (int k = 0; k < D; ++k) acc = fmaf(u[k], W[k * D + tid], acc);
    acc = fmaxf(acc, 0.f);
    y[g * D + tid] = acc;
    atomicAdd(&ystats[tid], acc);
    atomicAdd(&ystats[D + tid], acc * acc);
}

__global__ void fc_bn(const float* __restrict__ y, const float* __restrict__ ystats,
                      const float* __restrict__ gamma, const float* __restrict__ beta,
                      float* __restrict__ gbuf, float* __restrict__ total, int first) {
    int idx = blockIdx.x * blockDim.x + threadIdx.x;  // NG*D
    int d = idx & 127;
    const float invG = 1.f / NG;
    float m = ystats[d] * invG;
    float var = fmaxf(ystats[D + d] * invG - m * m, 0.f);
    float rs = rsqrtf(var + BN_EPS);
    float gv = (y[idx] - m) * rs * gamma[d] + beta[d];
    gbuf[idx] = gv;
    total[idx] = first ? gv : (total[idx] + gv);
}

__global__ void final_logits(const float* __restrict__ total, const float* __restrict__ linW,
                             const float* __restrict__ linb, float* __restrict__ out) {
    int g = blockIdx.x;
    int tid = threadIdx.x;  // D
    __shared__ float t[D];
    __shared__ float lg[12];
    t[tid] = total[g * D + tid];
    __syncthreads();
    if (tid < NC) {
        float a = linb[tid];
        for (int k = 0; k < D; ++k) a = fmaf(t[k], linW[k * NC + tid], a);
        lg[tid] = a;
    }
    __syncthreads();
    if (tid == 0) {
        float mx = lg[0];
        for (int c = 1; c < NC; ++c) mx = fmaxf(mx, lg[c]);
        float se = 0.f;
        for (int c = 0; c < NC; ++c) se += expf(lg[c] - mx);
        lg[10] = mx + logf(se);
    }
    __syncthreads();
    if (tid < NC) out[g * NC + tid] = lg[tid] - lg[10];
}

// ---------------- host ----------------
extern "C" void kernel_launch(void* const* d_in, const int* in_sizes, int n_in,
                              void* d_out, int out_size, void* d_ws, size_t ws_size,
                              hipStream_t stream) {
    const float* x = (const float*)d_in[0];
    const int* edge = (const int*)d_in[1];
    const int* batch = (const int*)d_in[2];
    const float* convW1 = (const float*)d_in[3];
    const float* convb1 = (const float*)d_in[4];
    const float* convW2 = (const float*)d_in[5];
    const float* convb2 = (const float*)d_in[6];
    const float* convgamma = (const float*)d_in[7];
    const float* convbeta = (const float*)d_in[8];
    const float* fc1W = (const float*)d_in[9];
    const float* fc1b = (const float*)d_in[10];
    const float* fc1gamma = (const float*)d_in[11];
    const float* fc1beta = (const float*)d_in[12];
    const float* fc2W = (const float*)d_in[13];
    const float* fc2b = (const float*)d_in[14];
    const float* fc2gamma = (const float*)d_in[15];
    const float* fc2beta = (const float*)d_in[16];
    const float* linW = (const float*)d_in[17];
    const float* linb = (const float*)d_in[18];

    const int N = in_sizes[0] / D;
    const int E = in_sizes[1] / 2;
    const int* srcs = edge;
    const int* dsts = edge + E;
    const float invN = 1.f / (float)N;

    char* p = (char*)d_ws;
    auto alloc = [&](size_t bytes) -> void* {
        void* r = (void*)p;
        p += (bytes + 255) & ~(size_t)255;
        return r;
    };
    uint* xb = (uint*)alloc((size_t)N * 64 * 4);   // bf16 x
    uint* z  = (uint*)alloc((size_t)N * 64 * 4);   // agg out
    uint* z1 = (uint*)alloc((size_t)N * 64 * 4);   // gemm1 out
    uint* zB = (uint*)alloc((size_t)N * 64 * 4);   // gemm2 out (= next src)
    ushort* wt = (ushort*)alloc((size_t)10 * D * D * 2);
    int* csr = (int*)alloc((size_t)E * 4);
    int* row_start = (int*)alloc((size_t)(N + 1) * 4);
    int* cursor = (int*)alloc((size_t)N * 4);
    int* cnt = (int*)alloc((size_t)N * 4);
    int* gstart = (int*)alloc((size_t)(NG + 1) * 4);
    int* ghist = (int*)alloc((size_t)NG * 4);
    float* pool = (float*)alloc((size_t)NG * D * 4);
    float* stats = (float*)alloc((size_t)2 * D * 4);
    float* ystats = (float*)alloc((size_t)2 * D * 4);
    float* ybuf = (float*)alloc((size_t)NG * D * 4);
    float* gbuf = (float*)alloc((size_t)NG * D * 4);
    float* total = (float*)alloc((size_t)NG * D * 4);

    // ---- preprocessing ----
    zero_ints<<<256, 256, 0, stream>>>(cnt, N);
    zero_ints<<<2, 256, 0, stream>>>(ghist, NG);
    hist_i32<<<2048, 256, 0, stream>>>(dsts, E, cnt);
    hist_i32<<<512, 256, 0, stream>>>(batch, N, ghist);
    scan_small<<<1, 1024, 0, stream>>>(cnt, N, row_start, cursor);
    scan_small<<<1, 1024, 0, stream>>>(ghist, NG, gstart, nullptr);
    fill_csr<<<2048, 256, 0, stream>>>(srcs, dsts, E, cursor, csr);
    cvt_bf16<<<2048, 256, 0, stream>>>(x, xb, N * 64);
    prep_w<<<10, 256, 0, stream>>>(convW1, convW2, wt);

    // ---- g0 path (exact fp32 pooling of x) ----
    pool_stats<0><<<NG, 256, 0, stream>>>(x, gstart, pool, nullptr);
    zero_ints<<<1, 256, 0, stream>>>((int*)ystats, 2 * D);
    fc_forward<<<NG, D, 0, stream>>>(pool, nullptr, nullptr, nullptr, 0.f, nullptr, nullptr,
                                     fc1W, fc1b, ybuf, ystats);
    fc_bn<<<(NG * D) / 256, 256, 0, stream>>>(ybuf, ystats, fc1gamma, fc1beta, gbuf, total, 1);

    // ---- 5 GIN layers ----
    const uint* src = xb;
    const int gemm_grid = (N + 63) / 64;
    for (int i = 0; i < 5; ++i) {
        const float* st = (i == 0) ? nullptr : stats;
        const float* ga = (i == 0) ? nullptr : (convgamma + (size_t)(i - 1) * D);
        const float* be = (i == 0) ? nullptr : (convbeta + (size_t)(i - 1) * D);
        agg_kernel<<<2048, 256, 0, stream>>>(src, st, ga, be, invN, row_start, csr, z, N);
        gemm_mfma<<<gemm_grid, 256, 0, stream>>>(z, wt + (size_t)i * D * D,
                                                 convb1 + (size_t)i * D, z1, N);
        gemm_mfma<<<gemm_grid, 256, 0, stream>>>(z1, wt + (size_t)(5 + i) * D * D,
                                                 convb2 + (size_t)i * D, zB, N);
        zero_ints<<<1, 256, 0, stream>>>((int*)stats, 2 * D);
        pool_stats<1><<<NG, 256, 0, stream>>>(zB, gstart, pool, stats);
        zero_ints<<<1, 256, 0, stream>>>((int*)ystats, 2 * D);
        fc_forward<<<NG, D, 0, stream>>>(pool, stats, convgamma + (size_t)i * D, convbeta + (size_t)i * D,
                                         invN, gstart, gbuf, fc2W, fc2b, ybuf, ystats);
        fc_bn<<<(NG * D) / 256, 256, 0, stream>>>(ybuf, ystats, fc2gamma, fc2beta, gbuf, total, 0);
        src = zB;
    }

    // ---- classifier ----
    final_logits<<<NG, D, 0, stream>>>(total, linW, linb, (float*)d_out);
}